// Round 12
// baseline (615.112 us; speedup 1.0000x reference)
//
#include <hip/hip_runtime.h>
#include <hip/hip_bf16.h>

typedef __attribute__((ext_vector_type(8))) short short8;
typedef __attribute__((ext_vector_type(4))) float f32x4;

#define GLOAD_LDS16(gp, lp)                                                      \
  __builtin_amdgcn_global_load_lds(                                              \
      (const __attribute__((address_space(1))) void*)(gp),                       \
      (__attribute__((address_space(3))) void*)(lp), 16, 0, 0)

#define SBAR() asm volatile("s_barrier" ::: "memory")
#define VMC(n)                                                                   \
  do {                                                                           \
    asm volatile("s_waitcnt vmcnt(" #n ")" ::: "memory");                        \
    __builtin_amdgcn_sched_barrier(0);                                           \
  } while (0)

__device__ __forceinline__ unsigned short f2bf_rne(float f) {
  union { float f; unsigned int u; } v; v.f = f;
  unsigned int u = v.u;
  u += 0x7fffu + ((u >> 16) & 1u);
  return (unsigned short)(u >> 16);
}

__device__ __forceinline__ short8 pack8(f32x4 a, f32x4 b) {
  short8 o;
  o[0] = (short)f2bf_rne(a[0]); o[1] = (short)f2bf_rne(a[1]);
  o[2] = (short)f2bf_rne(a[2]); o[3] = (short)f2bf_rne(a[3]);
  o[4] = (short)f2bf_rne(b[0]); o[5] = (short)f2bf_rne(b[1]);
  o[6] = (short)f2bf_rne(b[2]); o[7] = (short)f2bf_rne(b[3]);
  return o;
}

// ---------------------------------------------------------------- convert ----
__global__ void cvt_f32_bf16(const float* __restrict__ src,
                             unsigned short* __restrict__ dst, int n8) {
  int i = blockIdx.x * blockDim.x + threadIdx.x;
  int stride = gridDim.x * blockDim.x;
  const f32x4* s4 = (const f32x4*)src;
  short8* d8 = (short8*)dst;
  for (; i < n8; i += stride) {
    d8[i] = pack8(s4[2 * i], s4[2 * i + 1]);
  }
}

// ------------------- fused: xb = bf16(x);  T = mask * 2 * (x @ A^T) ----------
// One pass over x (f32): convert in-register, write xb, stage tile to padded
// LDS (stride 72 els -> <=2-way bank aliasing = free), MFMA vs in-kernel-
// converted A.  Replaces cvt_x + cvt_A + lora_t (removes the 128MB xb re-read).
__global__ __launch_bounds__(256) void cvt_lora_kernel(
    const float* __restrict__ x,     // [16384][4096] f32
    const float* __restrict__ A,     // [32][4096]    f32
    const int* __restrict__ offs,    // [4]
    unsigned short* __restrict__ xb, // [16384][4096] bf16 out
    unsigned short* __restrict__ T)  // [16384][32]   bf16 out
{
  __shared__ unsigned short xs[64 * 72];
  __shared__ unsigned short as_[32 * 72];
  const int t = threadIdx.x;
  const int m0 = blockIdx.x * 64;
  const int l = t & 63, w = t >> 6;
  const int lr = l & 15, lk = (l >> 4) * 8;
  const int arow = t >> 3, acol = (t & 7) * 8;
  f32x4 acc0 = {0, 0, 0, 0}, acc1 = {0, 0, 0, 0};
  for (int kt = 0; kt < 64; ++kt) {
    const int kof = kt * 64 + acol;
    const float* px0 = x + (size_t)(m0 + arow) * 4096 + kof;
    const float* px1 = x + (size_t)(m0 + 32 + arow) * 4096 + kof;
    const float* pa  = A + (size_t)arow * 4096 + kof;
    short8 s0 = pack8(*(const f32x4*)px0, *(const f32x4*)(px0 + 4));
    short8 s1 = pack8(*(const f32x4*)px1, *(const f32x4*)(px1 + 4));
    short8 sa = pack8(*(const f32x4*)pa,  *(const f32x4*)(pa + 4));
    *(short8*)(xb + (size_t)(m0 + arow) * 4096 + kof)      = s0;
    *(short8*)(xb + (size_t)(m0 + 32 + arow) * 4096 + kof) = s1;
    __syncthreads();                       // prior-iter LDS reads complete
    *(short8*)&xs[arow * 72 + acol]        = s0;
    *(short8*)&xs[(32 + arow) * 72 + acol] = s1;
    *(short8*)&as_[arow * 72 + acol]       = sa;
    __syncthreads();
#pragma unroll
    for (int kk = 0; kk < 2; ++kk) {
      short8 a  = *(const short8*)&xs[(w * 16 + lr) * 72 + kk * 32 + lk];
      short8 b0 = *(const short8*)&as_[lr * 72 + kk * 32 + lk];
      short8 b1 = *(const short8*)&as_[(16 + lr) * 72 + kk * 32 + lk];
      acc0 = __builtin_amdgcn_mfma_f32_16x16x32_bf16(a, b0, acc0, 0, 0, 0);
      acc1 = __builtin_amdgcn_mfma_f32_16x16x32_bf16(a, b1, acc1, 0, 0, 0);
    }
  }
  const int rowb = (l >> 4) * 4;
#pragma unroll
  for (int j = 0; j < 4; ++j) {
    int m = m0 + w * 16 + rowb + j;
    int bb = m >> 12, s = m & 4095;
    int kcut = offs[bb]; if (kcut > 4096) kcut = 4096;
    bool keep = s >= 4096 - kcut;
    T[(size_t)m * 32 + lr]      = keep ? f2bf_rne(2.0f * acc0[j]) : (unsigned short)0;
    T[(size_t)m * 32 + 16 + lr] = keep ? f2bf_rne(2.0f * acc1[j]) : (unsigned short)0;
  }
}

// ------------------------------------------------------------- main GEMM -----
// R11 structure unchanged (best measured: 256x256, BK=64, 2 slots, 8 waves,
// 16x16x32 MFMA, quarter-wave swizzle chunk^=(row&7) -> ZERO bank conflicts,
// m201-style 2 waits/iter).  Only change: LoRA prestep reads Bw as f32 and
// converts in-register (drops the cvt_Bw launch; Bw is 512KB, L2-resident).
__global__ __launch_bounds__(512, 2) void gemm_kernel(
    const unsigned short* __restrict__ xb,   // [16384][4096] bf16
    const unsigned short* __restrict__ Wb,   // [4096][4096]  bf16
    const unsigned short* __restrict__ Tm,   // [16384][32]   bf16 (mask+scale)
    const float* __restrict__ Bw,            // [4096][32]    f32
    const float* __restrict__ bias,          // [4096]
    float* __restrict__ out)                 // [16384][4096] f32
{
  constexpr int K = 4096;
  extern __shared__ char smem[];             // 128 KiB

  const int bid = blockIdx.x;
  const int swz = (bid & 7) * 128 + (bid >> 3);
  const int m0 = (swz >> 4) * 256;
  const int n0 = (swz & 15) * 256;

  const int t = threadIdx.x;
  const int l = t & 63, w = t >> 6;
  const int wqr = w >> 2;
  const int pr = (w >> 1) & 1;
  const int pc = w & 1;
  const int lr = l & 15, hi = l >> 4;
  const int e0 = (hi ^ (lr & 7)) * 8;        // verified zero-conflict swizzle

  const int srow = t >> 3;
  const int schunk = ((t & 7) ^ ((t >> 3) & 7)) * 8;
  const unsigned short* pA0 = xb + (size_t)(m0 + srow) * K + schunk;
  const unsigned short* pA1 = xb + (size_t)(m0 + 128 + srow) * K + schunk;
  const unsigned short* pB0 = Wb + (size_t)(n0 + srow) * K + schunk;
  const unsigned short* pB1 = Wb + (size_t)(n0 + 128 + srow) * K + schunk;
  unsigned short* sm = (unsigned short*)smem;
  const int ldst = t * 16;

#define STG(PTR, SLOT, ISB, HALF, KT)                                           \
  do {                                                                          \
    const unsigned short* g_ = (PTR) + (KT) * 64;                               \
    char* d_ = smem + (SLOT) * 65536 + (ISB) * 32768 + (HALF) * 16384 + ldst;   \
    GLOAD_LDS16(g_, d_);                                                        \
    GLOAD_LDS16(g_ + (size_t)64 * K, d_ + 8192);                                \
  } while (0)

  f32x4 acc[2][4][4];
  short8 afr[4];   // persists across the qc1 phase (A reuse)

  // --- LoRA prestep: register-direct (L2-resident), initializes acc ---
  {
    const unsigned short* tp = Tm + (size_t)(m0 + wqr * 128 + pr * 64 + lr) * 32 + hi * 8;
    short8 la[4];
#pragma unroll
    for (int i = 0; i < 4; ++i) la[i] = *(const short8*)(tp + i * 512);
    short8 lb[2][4];
#pragma unroll
    for (int qc = 0; qc < 2; ++qc)
#pragma unroll
      for (int j = 0; j < 4; ++j) {
        const float* bp = Bw + (size_t)(n0 + qc * 128 + pc * 64 + j * 16 + lr) * 32 + hi * 8;
        lb[qc][j] = pack8(*(const f32x4*)bp, *(const f32x4*)(bp + 4));
      }
#pragma unroll
    for (int qc = 0; qc < 2; ++qc)
#pragma unroll
      for (int i = 0; i < 4; ++i)
#pragma unroll
        for (int j = 0; j < 4; ++j)
          acc[qc][i][j] = __builtin_amdgcn_mfma_f32_16x16x32_bf16(
              la[i], lb[qc][j], (f32x4){0.f, 0.f, 0.f, 0.f}, 0, 0, 0);
  }

  // prologue: tile0 all 4 halves + s1.B0@1; VMC(2) leaves s1.B0 in flight.
  STG(pB1, 0, 1, 1, 0);
  STG(pA0, 0, 0, 0, 0);
  STG(pA1, 0, 0, 1, 0);
  STG(pB0, 0, 1, 0, 0);
  STG(pB0, 1, 1, 0, 1);
  VMC(2);
  SBAR();

#define PHASE(SLOT, QC, KK, READA, STG_STMT, WAIT_STMT)                         \
  {                                                                             \
    const unsigned short* Ah = sm + (SLOT) * 32768 + wqr * 8192;                \
    const unsigned short* Bh = sm + (SLOT) * 32768 + 16384 + (QC) * 8192;       \
    const int ek = e0 ^ ((KK) * 32);                                            \
    if (READA) {                                                                \
      _Pragma("unroll")                                                         \
      for (int i = 0; i < 4; ++i)                                               \
        afr[i] = *(const short8*)(Ah + (pr * 64 + i * 16 + lr) * 64 + ek);      \
    }                                                                           \
    short8 bfr[4];                                                              \
    _Pragma("unroll")                                                           \
    for (int j = 0; j < 4; ++j)                                                 \
      bfr[j] = *(const short8*)(Bh + (pc * 64 + j * 16 + lr) * 64 + ek);        \
    STG_STMT;                                                                   \
    SBAR();                                                                     \
    __builtin_amdgcn_s_setprio(1);                                              \
    _Pragma("unroll")                                                           \
    for (int i = 0; i < 4; ++i)                                                 \
      _Pragma("unroll")                                                         \
      for (int j = 0; j < 4; ++j)                                               \
        acc[QC][i][j] = __builtin_amdgcn_mfma_f32_16x16x32_bf16(                \
            afr[i], bfr[j], acc[QC][i][j], 0, 0, 0);                            \
    __builtin_amdgcn_s_setprio(0);                                              \
    WAIT_STMT;                                                                  \
    SBAR();                                                                     \
  }

  for (int I = 0; I < 31; ++I) {
    const int a = 2 * I;
    PHASE(0, 0, 0, 1, STG(pB1, 1, 1, 1, a + 1), ((void)0));
    PHASE(0, 1, 0, 0, STG(pA0, 1, 0, 0, a + 1), ((void)0));
    PHASE(0, 0, 1, 1, STG(pA1, 1, 0, 1, a + 1), ((void)0));
    PHASE(0, 1, 1, 0, STG(pB0, 0, 1, 0, a + 2), VMC(2));
    PHASE(1, 0, 0, 1, STG(pB1, 0, 1, 1, a + 2), ((void)0));
    PHASE(1, 1, 0, 0, STG(pA0, 0, 0, 0, a + 2), ((void)0));
    PHASE(1, 0, 1, 1, STG(pA1, 0, 0, 1, a + 2), ((void)0));
    PHASE(1, 1, 1, 0, STG(pB0, 1, 1, 0, a + 3), VMC(2));
  }
  PHASE(0, 0, 0, 1, STG(pB1, 1, 1, 1, 63), ((void)0));
  PHASE(0, 1, 0, 0, STG(pA0, 1, 0, 0, 63), ((void)0));
  PHASE(0, 0, 1, 1, STG(pA1, 1, 0, 1, 63), ((void)0));
  PHASE(0, 1, 1, 0, ((void)0), VMC(0));
  PHASE(1, 0, 0, 1, ((void)0), ((void)0));
  PHASE(1, 1, 0, 0, ((void)0), ((void)0));
  PHASE(1, 0, 1, 1, ((void)0), ((void)0));
  PHASE(1, 1, 1, 0, ((void)0), ((void)0));
#undef PHASE
#undef STG

  // epilogue: bias + store (C/D map: col=lr -> N, row=hi*4+e -> M)
  float bv[2][4];
#pragma unroll
  for (int qc = 0; qc < 2; ++qc)
#pragma unroll
    for (int j = 0; j < 4; ++j)
      bv[qc][j] = bias[n0 + qc * 128 + pc * 64 + j * 16 + lr];
  const int rowb = hi * 4;
#pragma unroll
  for (int qc = 0; qc < 2; ++qc)
#pragma unroll
    for (int i = 0; i < 4; ++i)
#pragma unroll
      for (int e = 0; e < 4; ++e) {
        int row = m0 + wqr * 128 + pr * 64 + i * 16 + rowb + e;
        float* orow = out + (size_t)row * 4096 + n0 + qc * 128 + pc * 64;
#pragma unroll
        for (int j = 0; j < 4; ++j) orow[j * 16 + lr] = acc[qc][i][j][e] + bv[qc][j];
      }
}

// ----------------------------------------------------------------- launch ----
extern "C" void kernel_launch(void* const* d_in, const int* in_sizes, int n_in,
                              void* d_out, int out_size, void* d_ws, size_t ws_size,
                              hipStream_t stream) {
  const float* x   = (const float*)d_in[0];
  const int* offs  = (const int*)d_in[1];
  const float* W   = (const float*)d_in[2];
  const float* b   = (const float*)d_in[3];
  const float* A   = (const float*)d_in[4];
  const float* Bw  = (const float*)d_in[5];
  float* out = (float*)d_out;

  char* ws = (char*)d_ws;
  unsigned short* xb = (unsigned short*)ws;                 // 134,217,728 B
  unsigned short* Wb = (unsigned short*)(ws + 134217728);   //  33,554,432 B
  unsigned short* T  = (unsigned short*)(ws + 167772160);   //   1,048,576 B

  hipFuncSetAttribute((const void*)gemm_kernel,
                      hipFuncAttributeMaxDynamicSharedMemorySize, 131072);

  cvt_lora_kernel<<<256, 256, 0, stream>>>(x, A, offs, xb, T);
  cvt_f32_bf16<<<2048, 256, 0, stream>>>(W, Wb, 16777216 / 8);
  gemm_kernel<<<1024, 512, 131072, stream>>>(xb, Wb, T, Bw, b, out);
}

// Round 13
// 581.370 us; speedup vs baseline: 1.0580x; 1.0580x over previous
//
#include <hip/hip_runtime.h>
#include <hip/hip_bf16.h>

typedef __attribute__((ext_vector_type(8))) short short8;
typedef __attribute__((ext_vector_type(4))) float f32x4;

#define GLOAD_LDS16(gp, lp)                                                      \
  __builtin_amdgcn_global_load_lds(                                              \
      (const __attribute__((address_space(1))) void*)(gp),                       \
      (__attribute__((address_space(3))) void*)(lp), 16, 0, 0)

#define SBAR() asm volatile("s_barrier" ::: "memory")
#define VMC(n)                                                                   \
  do {                                                                           \
    asm volatile("s_waitcnt vmcnt(" #n ")" ::: "memory");                        \
    __builtin_amdgcn_sched_barrier(0);                                           \
  } while (0)

__device__ __forceinline__ unsigned short f2bf_rne(float f) {
  union { float f; unsigned int u; } v; v.f = f;
  unsigned int u = v.u;
  u += 0x7fffu + ((u >> 16) & 1u);
  return (unsigned short)(u >> 16);
}

__device__ __forceinline__ short8 pack8(f32x4 a, f32x4 b) {
  short8 o;
  o[0] = (short)f2bf_rne(a[0]); o[1] = (short)f2bf_rne(a[1]);
  o[2] = (short)f2bf_rne(a[2]); o[3] = (short)f2bf_rne(a[3]);
  o[4] = (short)f2bf_rne(b[0]); o[5] = (short)f2bf_rne(b[1]);
  o[6] = (short)f2bf_rne(b[2]); o[7] = (short)f2bf_rne(b[3]);
  return o;
}

// ---------------------------------------------------------------- convert ----
__global__ void cvt_f32_bf16(const float* __restrict__ src,
                             unsigned short* __restrict__ dst, int n8) {
  int i = blockIdx.x * blockDim.x + threadIdx.x;
  int stride = gridDim.x * blockDim.x;
  const f32x4* s4 = (const f32x4*)src;
  short8* d8 = (short8*)dst;
  for (; i < n8; i += stride) {
    d8[i] = pack8(s4[2 * i], s4[2 * i + 1]);
  }
}

// ---- fused: xb = bf16(x);  T = mask*2*(x@A^T);  Wb chunk = bf16(W chunk) ----
// v2: 512 blocks x 32 rows (2 blocks/CU -> cross-block load/MFMA overlap; A is
// L2-resident so the extra A re-reads are free).  W conversion folded into the
// tail (1/512 of W per block) -- removes the serial cvt_W dispatch.
__global__ __launch_bounds__(256) void cvt_lora_kernel(
    const float* __restrict__ x,     // [16384][4096] f32
    const float* __restrict__ A,     // [32][4096]    f32
    const float* __restrict__ W,     // [4096][4096]  f32
    const int* __restrict__ offs,    // [4]
    unsigned short* __restrict__ xb, // [16384][4096] bf16 out
    unsigned short* __restrict__ Wb, // [4096][4096]  bf16 out
    unsigned short* __restrict__ T)  // [16384][32]   bf16 out
{
  __shared__ unsigned short xs[32 * 72];
  __shared__ unsigned short as_[32 * 72];
  const int t = threadIdx.x;
  const int m0 = blockIdx.x * 32;
  const int l = t & 63, w = t >> 6;
  const int wr = w >> 1, wc = w & 1;         // 2x2: 16-row half x 16-col half
  const int lr = l & 15, lk = (l >> 4) * 8;
  const int arow = t >> 3, acol = (t & 7) * 8;
  f32x4 acc = {0, 0, 0, 0};
  for (int kt = 0; kt < 64; ++kt) {
    const int kof = kt * 64 + acol;
    const float* px = x + (size_t)(m0 + arow) * 4096 + kof;
    const float* pa = A + (size_t)arow * 4096 + kof;
    short8 s0 = pack8(*(const f32x4*)px, *(const f32x4*)(px + 4));
    short8 sa = pack8(*(const f32x4*)pa, *(const f32x4*)(pa + 4));
    *(short8*)(xb + (size_t)(m0 + arow) * 4096 + kof) = s0;
    __syncthreads();                         // prior-iter LDS reads complete
    *(short8*)&xs[arow * 72 + acol]  = s0;
    *(short8*)&as_[arow * 72 + acol] = sa;
    __syncthreads();
#pragma unroll
    for (int kk = 0; kk < 2; ++kk) {
      short8 a = *(const short8*)&xs[(wr * 16 + lr) * 72 + kk * 32 + lk];
      short8 b = *(const short8*)&as_[(wc * 16 + lr) * 72 + kk * 32 + lk];
      acc = __builtin_amdgcn_mfma_f32_16x16x32_bf16(a, b, acc, 0, 0, 0);
    }
  }
  const int rowb = (l >> 4) * 4;
#pragma unroll
  for (int j = 0; j < 4; ++j) {
    int m = m0 + wr * 16 + rowb + j;
    int bb = m >> 12, s = m & 4095;
    int kcut = offs[bb]; if (kcut > 4096) kcut = 4096;
    bool keep = s >= 4096 - kcut;
    T[(size_t)m * 32 + wc * 16 + lr] = keep ? f2bf_rne(2.0f * acc[j]) : (unsigned short)0;
  }
  // tail: convert this block's 1/512 slice of W (4096 short8 = 32 KB bf16)
  const f32x4* s4 = (const f32x4*)W;
  short8* d8 = (short8*)Wb;
  const int base = blockIdx.x * 4096;
#pragma unroll
  for (int q = 0; q < 16; ++q) {
    int idx = base + q * 256 + t;
    d8[idx] = pack8(s4[2 * idx], s4[2 * idx + 1]);
  }
}

// ------------------------------------------------------------- main GEMM -----
// EXACT R11 kernel (best measured: 473-480us, 1163 TF, MfmaUtil ~52%, ZERO
// bank conflicts).  256x256 tile, BK=64, 2 slots, 8 waves, 16x16x32 MFMA,
// quarter-wave swizzle chunk^=(row&7), m201-style 2 counted waits per iter.
__global__ __launch_bounds__(512, 2) void gemm_kernel(
    const unsigned short* __restrict__ xb,   // [16384][4096] bf16
    const unsigned short* __restrict__ Wb,   // [4096][4096]  bf16
    const unsigned short* __restrict__ Tm,   // [16384][32]   bf16 (mask+scale)
    const unsigned short* __restrict__ Bwb,  // [4096][32]    bf16
    const float* __restrict__ bias,          // [4096]
    float* __restrict__ out)                 // [16384][4096] f32
{
  constexpr int K = 4096;
  extern __shared__ char smem[];             // 128 KiB

  const int bid = blockIdx.x;
  const int swz = (bid & 7) * 128 + (bid >> 3);
  const int m0 = (swz >> 4) * 256;
  const int n0 = (swz & 15) * 256;

  const int t = threadIdx.x;
  const int l = t & 63, w = t >> 6;
  const int wqr = w >> 2;
  const int pr = (w >> 1) & 1;
  const int pc = w & 1;
  const int lr = l & 15, hi = l >> 4;
  const int e0 = (hi ^ (lr & 7)) * 8;        // verified zero-conflict swizzle

  const int srow = t >> 3;
  const int schunk = ((t & 7) ^ ((t >> 3) & 7)) * 8;
  const unsigned short* pA0 = xb + (size_t)(m0 + srow) * K + schunk;
  const unsigned short* pA1 = xb + (size_t)(m0 + 128 + srow) * K + schunk;
  const unsigned short* pB0 = Wb + (size_t)(n0 + srow) * K + schunk;
  const unsigned short* pB1 = Wb + (size_t)(n0 + 128 + srow) * K + schunk;
  unsigned short* sm = (unsigned short*)smem;
  const int ldst = t * 16;

#define STG(PTR, SLOT, ISB, HALF, KT)                                           \
  do {                                                                          \
    const unsigned short* g_ = (PTR) + (KT) * 64;                               \
    char* d_ = smem + (SLOT) * 65536 + (ISB) * 32768 + (HALF) * 16384 + ldst;   \
    GLOAD_LDS16(g_, d_);                                                        \
    GLOAD_LDS16(g_ + (size_t)64 * K, d_ + 8192);                                \
  } while (0)

  f32x4 acc[2][4][4];
  short8 afr[4];   // persists across the qc1 phase (A reuse)

  // --- LoRA prestep: register-direct (L2-resident), initializes acc ---
  {
    const unsigned short* tp = Tm + (size_t)(m0 + wqr * 128 + pr * 64 + lr) * 32 + hi * 8;
    short8 la[4];
#pragma unroll
    for (int i = 0; i < 4; ++i) la[i] = *(const short8*)(tp + i * 512);
    short8 lb[2][4];
#pragma unroll
    for (int qc = 0; qc < 2; ++qc)
#pragma unroll
      for (int j = 0; j < 4; ++j)
        lb[qc][j] = *(const short8*)(Bwb + (size_t)(n0 + qc * 128 + pc * 64 + j * 16 + lr) * 32 + hi * 8);
#pragma unroll
    for (int qc = 0; qc < 2; ++qc)
#pragma unroll
      for (int i = 0; i < 4; ++i)
#pragma unroll
        for (int j = 0; j < 4; ++j)
          acc[qc][i][j] = __builtin_amdgcn_mfma_f32_16x16x32_bf16(
              la[i], lb[qc][j], (f32x4){0.f, 0.f, 0.f, 0.f}, 0, 0, 0);
  }

  // prologue: tile0 all 4 halves + s1.B0@1; VMC(2) leaves s1.B0 in flight.
  STG(pB1, 0, 1, 1, 0);
  STG(pA0, 0, 0, 0, 0);
  STG(pA1, 0, 0, 1, 0);
  STG(pB0, 0, 1, 0, 0);
  STG(pB0, 1, 1, 0, 1);
  VMC(2);
  SBAR();

#define PHASE(SLOT, QC, KK, READA, STG_STMT, WAIT_STMT)                         \
  {                                                                             \
    const unsigned short* Ah = sm + (SLOT) * 32768 + wqr * 8192;                \
    const unsigned short* Bh = sm + (SLOT) * 32768 + 16384 + (QC) * 8192;       \
    const int ek = e0 ^ ((KK) * 32);                                            \
    if (READA) {                                                                \
      _Pragma("unroll")                                                         \
      for (int i = 0; i < 4; ++i)                                               \
        afr[i] = *(const short8*)(Ah + (pr * 64 + i * 16 + lr) * 64 + ek);      \
    }                                                                           \
    short8 bfr[4];                                                              \
    _Pragma("unroll")                                                           \
    for (int j = 0; j < 4; ++j)                                                 \
      bfr[j] = *(const short8*)(Bh + (pc * 64 + j * 16 + lr) * 64 + ek);        \
    STG_STMT;                                                                   \
    SBAR();                                                                     \
    __builtin_amdgcn_s_setprio(1);                                              \
    _Pragma("unroll")                                                           \
    for (int i = 0; i < 4; ++i)                                                 \
      _Pragma("unroll")                                                         \
      for (int j = 0; j < 4; ++j)                                               \
        acc[QC][i][j] = __builtin_amdgcn_mfma_f32_16x16x32_bf16(                \
            afr[i], bfr[j], acc[QC][i][j], 0, 0, 0);                            \
    __builtin_amdgcn_s_setprio(0);                                              \
    WAIT_STMT;                                                                  \
    SBAR();                                                                     \
  }

  for (int I = 0; I < 31; ++I) {
    const int a = 2 * I;
    PHASE(0, 0, 0, 1, STG(pB1, 1, 1, 1, a + 1), ((void)0));
    PHASE(0, 1, 0, 0, STG(pA0, 1, 0, 0, a + 1), ((void)0));
    PHASE(0, 0, 1, 1, STG(pA1, 1, 0, 1, a + 1), ((void)0));
    PHASE(0, 1, 1, 0, STG(pB0, 0, 1, 0, a + 2), VMC(2));
    PHASE(1, 0, 0, 1, STG(pB1, 0, 1, 1, a + 2), ((void)0));
    PHASE(1, 1, 0, 0, STG(pA0, 0, 0, 0, a + 2), ((void)0));
    PHASE(1, 0, 1, 1, STG(pA1, 0, 0, 1, a + 2), ((void)0));
    PHASE(1, 1, 1, 0, STG(pB0, 1, 1, 0, a + 3), VMC(2));
  }
  PHASE(0, 0, 0, 1, STG(pB1, 1, 1, 1, 63), ((void)0));
  PHASE(0, 1, 0, 0, STG(pA0, 1, 0, 0, 63), ((void)0));
  PHASE(0, 0, 1, 1, STG(pA1, 1, 0, 1, 63), ((void)0));
  PHASE(0, 1, 1, 0, ((void)0), VMC(0));
  PHASE(1, 0, 0, 1, ((void)0), ((void)0));
  PHASE(1, 1, 0, 0, ((void)0), ((void)0));
  PHASE(1, 0, 1, 1, ((void)0), ((void)0));
  PHASE(1, 1, 1, 0, ((void)0), ((void)0));
#undef PHASE
#undef STG

  // epilogue: bias + store (C/D map: col=lr -> N, row=hi*4+e -> M)
  float bv[2][4];
#pragma unroll
  for (int qc = 0; qc < 2; ++qc)
#pragma unroll
    for (int j = 0; j < 4; ++j)
      bv[qc][j] = bias[n0 + qc * 128 + pc * 64 + j * 16 + lr];
  const int rowb = hi * 4;
#pragma unroll
  for (int qc = 0; qc < 2; ++qc)
#pragma unroll
    for (int i = 0; i < 4; ++i)
#pragma unroll
      for (int e = 0; e < 4; ++e) {
        int row = m0 + wqr * 128 + pr * 64 + i * 16 + rowb + e;
        float* orow = out + (size_t)row * 4096 + n0 + qc * 128 + pc * 64;
#pragma unroll
        for (int j = 0; j < 4; ++j) orow[j * 16 + lr] = acc[qc][i][j][e] + bv[qc][j];
      }
}

// ----------------------------------------------------------------- launch ----
extern "C" void kernel_launch(void* const* d_in, const int* in_sizes, int n_in,
                              void* d_out, int out_size, void* d_ws, size_t ws_size,
                              hipStream_t stream) {
  const float* x   = (const float*)d_in[0];
  const int* offs  = (const int*)d_in[1];
  const float* W   = (const float*)d_in[2];
  const float* b   = (const float*)d_in[3];
  const float* A   = (const float*)d_in[4];
  const float* Bw  = (const float*)d_in[5];
  float* out = (float*)d_out;

  char* ws = (char*)d_ws;
  unsigned short* xb  = (unsigned short*)ws;                 // 134,217,728 B
  unsigned short* Wb  = (unsigned short*)(ws + 134217728);   //  33,554,432 B
  unsigned short* Bwb = (unsigned short*)(ws + 167772160);   //     262,144 B
  unsigned short* T   = (unsigned short*)(ws + 168034304);   //   1,048,576 B

  hipFuncSetAttribute((const void*)gemm_kernel,
                      hipFuncAttributeMaxDynamicSharedMemorySize, 131072);

  cvt_f32_bf16<<<64, 256, 0, stream>>>(Bw, Bwb, 131072 / 8);
  cvt_lora_kernel<<<512, 256, 0, stream>>>(x, A, W, offs, xb, Wb, T);
  gemm_kernel<<<1024, 512, 131072, stream>>>(xb, Wb, T, Bwb, b, out);
}